// Round 6
// baseline (548.839 us; speedup 1.0000x reference)
//
#include <hip/hip_runtime.h>

// ---------------- problem constants ----------------
#define CCH   19
#define HWSZ  262144          // 512*512
#define NPIX  4194304         // 16*512*512
#define NMIN  262144
#define THRESH_F 0.35667494393873245f   // float32(-log(0.7))

// hist sizes: radix select on float bits, 11 + 11 + 10 bits
#define NB1 2048
#define NB2 2048
#define NB3 1024

// ---------------- kernel 1: CE loss + level-1 hist + thresh sum/count ------
// 4 pixels per thread via float4 loads (16B/lane coalescing sweet spot).
// NPIX/4 = 2^20 = 2048 blocks * 256 threads * 2 iterations exactly.
__global__ __launch_bounds__(256) void k_compute4(
    const float* __restrict__ inp, const int* __restrict__ tgt,
    float4* __restrict__ loss4, unsigned int* __restrict__ hist1,
    double* __restrict__ sumT, unsigned long long* __restrict__ cntT)
{
    __shared__ unsigned int sh[NB1];
    for (int i = threadIdx.x; i < NB1; i += 256) sh[i] = 0;
    __syncthreads();

    float ls = 0.f;
    unsigned int lc = 0;
    const unsigned int stride = gridDim.x * 256;

    for (unsigned int i = blockIdx.x * 256 + threadIdx.x; i < NPIX / 4; i += stride) {
        const unsigned int p  = i * 4;            // first pixel of the group
        const unsigned int b  = p >> 18;          // p / HWSZ (group never spans b)
        const unsigned int hw = p & (HWSZ - 1);
        const float* base = inp + (size_t)b * (CCH * HWSZ) + hw;
        const int4 t4 = *(const int4*)(tgt + p);

        float4 x[CCH];
        float4 m  = make_float4(-3.4e38f, -3.4e38f, -3.4e38f, -3.4e38f);
        float4 xt = make_float4(0.f, 0.f, 0.f, 0.f);
        #pragma unroll
        for (int c = 0; c < CCH; ++c) {
            const float4 v = *(const float4*)(base + (size_t)c * HWSZ);
            x[c] = v;
            m.x = fmaxf(m.x, v.x); m.y = fmaxf(m.y, v.y);
            m.z = fmaxf(m.z, v.z); m.w = fmaxf(m.w, v.w);
            xt.x = (c == t4.x) ? v.x : xt.x;      // predicated, no runtime index
            xt.y = (c == t4.y) ? v.y : xt.y;
            xt.z = (c == t4.z) ? v.z : xt.z;
            xt.w = (c == t4.w) ? v.w : xt.w;
        }
        float4 s = make_float4(0.f, 0.f, 0.f, 0.f);
        #pragma unroll
        for (int c = 0; c < CCH; ++c) {
            s.x += __expf(x[c].x - m.x);
            s.y += __expf(x[c].y - m.y);
            s.z += __expf(x[c].z - m.z);
            s.w += __expf(x[c].w - m.w);
        }

        float4 l;
        l.x = (t4.x != 255) ? (__logf(s.x) + m.x - xt.x) : 0.f;
        l.y = (t4.y != 255) ? (__logf(s.y) + m.y - xt.y) : 0.f;
        l.z = (t4.z != 255) ? (__logf(s.z) + m.z - xt.z) : 0.f;
        l.w = (t4.w != 255) ? (__logf(s.w) + m.w - xt.w) : 0.f;
        l.x = fmaxf(l.x, 0.f); l.y = fmaxf(l.y, 0.f);     // keep bit-order valid
        l.z = fmaxf(l.z, 0.f); l.w = fmaxf(l.w, 0.f);
        loss4[i] = l;

        if (l.x > THRESH_F) { ls += l.x; lc++; }
        if (l.y > THRESH_F) { ls += l.y; lc++; }
        if (l.z > THRESH_F) { ls += l.z; lc++; }
        if (l.w > THRESH_F) { ls += l.w; lc++; }
        atomicAdd(&sh[__float_as_uint(l.x) >> 21], 1u);
        atomicAdd(&sh[__float_as_uint(l.y) >> 21], 1u);
        atomicAdd(&sh[__float_as_uint(l.z) >> 21], 1u);
        atomicAdd(&sh[__float_as_uint(l.w) >> 21], 1u);
    }

    // block-reduce ls / lc
    #pragma unroll
    for (int off = 32; off > 0; off >>= 1) {
        ls += __shfl_down(ls, off);
        lc += __shfl_down(lc, off);
    }
    __shared__ float wsum[4];
    __shared__ unsigned int wcnt[4];
    const int lane = threadIdx.x & 63, wid = threadIdx.x >> 6;
    if (lane == 0) { wsum[wid] = ls; wcnt[wid] = lc; }
    __syncthreads();
    if (threadIdx.x == 0) {
        atomicAdd(sumT, (double)(wsum[0] + wsum[1] + wsum[2] + wsum[3]));
        atomicAdd(cntT, (unsigned long long)(wcnt[0] + wcnt[1] + wcnt[2] + wcnt[3]));
    }

    __syncthreads();
    for (int i = threadIdx.x; i < NB1; i += 256) {
        unsigned int v = sh[i];
        if (v) atomicAdd(&hist1[i], v);   // skip-zero merge: hot bins only
    }
}

// ---------------- radix-select step (single block) -------------------------
// state.x = prefix bits so far, state.y = K remaining within current bucket
__global__ __launch_bounds__(256) void k_select(
    const unsigned int* __restrict__ hist, int nbins, int shiftbits, int first,
    uint2* __restrict__ state)
{
    __shared__ unsigned int cnt[NB1];
    __shared__ unsigned int psum[257];
    const int tid = threadIdx.x;

    for (int i = tid; i < nbins; i += 256) cnt[i] = hist[i];
    if (tid == 0) psum[256] = 0;
    __syncthreads();

    const int chunk = nbins >> 8;
    const int lo = tid * chunk, hi = lo + chunk;
    unsigned int s = 0;
    for (int b = lo; b < hi; ++b) s += cnt[b];
    psum[tid] = s;
    __syncthreads();

    // inclusive suffix-sum (Hillis-Steele)
    for (int d = 1; d < 256; d <<= 1) {
        unsigned int v = psum[tid] + ((tid + d < 256) ? psum[tid + d] : 0);
        __syncthreads();
        psum[tid] = v;
        __syncthreads();
    }

    const unsigned int K       = first ? (unsigned int)NMIN : state->y;
    const unsigned int oldpref = first ? 0u : state->x;
    __syncthreads();   // everyone has read old state before the winner writes

    const unsigned int above = psum[tid + 1];
    if (psum[tid] >= K && above < K) {          // crossing is in my chunk
        unsigned int cum = above;
        for (int b = hi - 1; b >= lo; --b) {
            const unsigned int prev = cum;
            cum += cnt[b];
            if (cum >= K) {
                state->x = (oldpref << shiftbits) | (unsigned int)b;
                state->y = K - prev;
                break;
            }
        }
    }
}

// ---------------- conditional histogram for levels 2/3 ---------------------
__global__ __launch_bounds__(256) void k_hist(
    const float4* __restrict__ loss4, const uint2* __restrict__ state,
    unsigned int* __restrict__ histo, int level)
{
    __shared__ unsigned int sh[NB2];
    const int nb = (level == 2) ? NB2 : NB3;
    for (int i = threadIdx.x; i < nb; i += 256) sh[i] = 0;
    __syncthreads();

    const unsigned int pref = state->x;
    const unsigned int stride = gridDim.x * 256;

    for (unsigned int i = blockIdx.x * 256 + threadIdx.x; i < NPIX / 4; i += stride) {
        const float4 v = loss4[i];
        const float vv[4] = {v.x, v.y, v.z, v.w};
        #pragma unroll
        for (int j = 0; j < 4; ++j) {
            const unsigned int bits = __float_as_uint(vv[j]);
            if (level == 2) {
                if ((bits >> 21) == pref) atomicAdd(&sh[(bits >> 10) & 0x7FF], 1u);
            } else {
                if ((bits >> 10) == pref) atomicAdd(&sh[bits & 0x3FF], 1u);
            }
        }
    }
    __syncthreads();
    for (int i = threadIdx.x; i < nb; i += 256) {
        unsigned int v = sh[i];
        if (v) atomicAdd(&histo[i], v);
    }
}

// ---------------- sum/count of elements strictly above t -------------------
__global__ __launch_bounds__(256) void k_sumtop(
    const float4* __restrict__ loss4, const uint2* __restrict__ state,
    double* __restrict__ sumG, unsigned long long* __restrict__ cntG)
{
    const unsigned int tb = state->x;   // full 32-bit pattern of t
    float ls = 0.f;
    unsigned int lc = 0;
    const unsigned int stride = gridDim.x * 256;

    for (unsigned int i = blockIdx.x * 256 + threadIdx.x; i < NPIX / 4; i += stride) {
        const float4 v = loss4[i];
        const float vv[4] = {v.x, v.y, v.z, v.w};
        #pragma unroll
        for (int j = 0; j < 4; ++j) {
            if (__float_as_uint(vv[j]) > tb) { ls += vv[j]; lc++; }
        }
    }
    #pragma unroll
    for (int off = 32; off > 0; off >>= 1) {
        ls += __shfl_down(ls, off);
        lc += __shfl_down(lc, off);
    }
    __shared__ float wsum[4];
    __shared__ unsigned int wcnt[4];
    const int lane = threadIdx.x & 63, wid = threadIdx.x >> 6;
    if (lane == 0) { wsum[wid] = ls; wcnt[wid] = lc; }
    __syncthreads();
    if (threadIdx.x == 0) {
        atomicAdd(sumG, (double)(wsum[0] + wsum[1] + wsum[2] + wsum[3]));
        atomicAdd(cntG, (unsigned long long)(wcnt[0] + wcnt[1] + wcnt[2] + wcnt[3]));
    }
}

// ---------------- finalize -------------------------------------------------
__global__ void k_finalize(
    const double* __restrict__ sumT, const unsigned long long* __restrict__ cntT,
    const uint2* __restrict__ state, const double* __restrict__ sumG,
    const unsigned long long* __restrict__ cntG, float* __restrict__ out)
{
    if (threadIdx.x == 0 && blockIdx.x == 0) {
        const unsigned long long c = *cntT;
        double r;
        if (c > (unsigned long long)NMIN) {
            r = *sumT / (double)c;                       // keep all > THRESH
        } else {
            const float t = __uint_as_float(state->x);   // N_MIN-th largest
            r = (*sumG + (double)(NMIN - *cntG) * (double)t) / (double)NMIN;
        }
        out[0] = (float)r;
    }
}

// ---------------- launch ---------------------------------------------------
extern "C" void kernel_launch(void* const* d_in, const int* in_sizes, int n_in,
                              void* d_out, int out_size, void* d_ws, size_t ws_size,
                              hipStream_t stream)
{
    const float* inp = (const float*)d_in[0];
    const int*   tgt = (const int*)d_in[1];
    float*       out = (float*)d_out;
    char*        ws  = (char*)d_ws;

    // workspace layout
    float* loss = (float*)ws;
    const size_t LOSS_BYTES = (size_t)NPIX * 4;                 // 16 MiB
    unsigned int* h1 = (unsigned int*)(ws + LOSS_BYTES);        // 2048
    unsigned int* h2 = h1 + NB1;                                // 2048
    unsigned int* h3 = h2 + NB2;                                // 1024
    char* scal = ws + LOSS_BYTES + (NB1 + NB2 + NB3) * 4;       // +20480
    double*             sumT  = (double*)(scal + 0);
    unsigned long long* cntT  = (unsigned long long*)(scal + 8);
    double*             sumG  = (double*)(scal + 16);
    unsigned long long* cntG  = (unsigned long long*)(scal + 24);
    uint2*              state = (uint2*)(scal + 32);
    const size_t AUX_BYTES = (NB1 + NB2 + NB3) * 4 + 40;

    // zero hists + accumulators (ws is poisoned 0xAA before every launch)
    hipMemsetAsync(ws + LOSS_BYTES, 0, AUX_BYTES, stream);

    // 1) CE loss + level-1 hist + above-threshold sum/count
    k_compute4<<<2048, 256, 0, stream>>>(inp, tgt, (float4*)loss, h1, sumT, cntT);
    // 2) radix select level 1 (top 11 bits)
    k_select<<<1, 256, 0, stream>>>(h1, NB1, 11, 1, state);
    // 3) level-2 hist (next 11 bits) among candidates
    k_hist<<<2048, 256, 0, stream>>>((const float4*)loss, state, h2, 2);
    k_select<<<1, 256, 0, stream>>>(h2, NB2, 11, 0, state);
    // 4) level-3 hist (last 10 bits)
    k_hist<<<2048, 256, 0, stream>>>((const float4*)loss, state, h3, 3);
    k_select<<<1, 256, 0, stream>>>(h3, NB3, 10, 0, state);
    // 5) sum/count strictly above t
    k_sumtop<<<2048, 256, 0, stream>>>((const float4*)loss, state, sumG, cntG);
    // 6) pick branch, write scalar
    k_finalize<<<1, 1, 0, stream>>>(sumT, cntT, state, sumG, cntG, out);
}

// Round 9
// 441.867 us; speedup vs baseline: 1.2421x; 1.2421x over previous
//
#include <hip/hip_runtime.h>

// ---------------- problem constants ----------------
#define CCH   19
#define HWSZ  262144          // 512*512
#define NPIX  4194304         // 16*512*512
#define NMIN  262144
#define THRESH_F 0.35667494393873245f   // float32(-log(0.7))

#define NBLK  1024            // grid for full-scan kernels (4 blocks/CU)

// hist sizes: radix select on float bits, 11 + 11 + 10 bits
#define NB1 2048
#define NB2 2048
#define NB3 1024

// ---------------- kernel 1: CE loss + level-1 hist + thresh sum/count ------
// 4 pixels per thread via float4 loads (16B/lane coalescing sweet spot).
// NPIX/4 = 2^20 = 1024 blocks * 256 threads * 4 iterations exactly.
__global__ __launch_bounds__(256) void k_compute4(
    const float* __restrict__ inp, const int* __restrict__ tgt,
    float4* __restrict__ loss4, unsigned int* __restrict__ hist1,
    double* __restrict__ sumT, unsigned long long* __restrict__ cntT)
{
    __shared__ unsigned int sh[NB1];
    for (int i = threadIdx.x; i < NB1; i += 256) sh[i] = 0;
    __syncthreads();

    float ls = 0.f;
    unsigned int lc = 0;
    const unsigned int stride = gridDim.x * 256;

    for (unsigned int i = blockIdx.x * 256 + threadIdx.x; i < NPIX / 4; i += stride) {
        const unsigned int p  = i * 4;            // first pixel of the group
        const unsigned int b  = p >> 18;          // p / HWSZ (group never spans b)
        const unsigned int hw = p & (HWSZ - 1);
        const float* base = inp + (size_t)b * (CCH * HWSZ) + hw;
        const int4 t4 = *(const int4*)(tgt + p);

        float4 x[CCH];
        float4 m  = make_float4(-3.4e38f, -3.4e38f, -3.4e38f, -3.4e38f);
        float4 xt = make_float4(0.f, 0.f, 0.f, 0.f);
        #pragma unroll
        for (int c = 0; c < CCH; ++c) {
            const float4 v = *(const float4*)(base + (size_t)c * HWSZ);
            x[c] = v;
            m.x = fmaxf(m.x, v.x); m.y = fmaxf(m.y, v.y);
            m.z = fmaxf(m.z, v.z); m.w = fmaxf(m.w, v.w);
            xt.x = (c == t4.x) ? v.x : xt.x;      // predicated, no runtime index
            xt.y = (c == t4.y) ? v.y : xt.y;
            xt.z = (c == t4.z) ? v.z : xt.z;
            xt.w = (c == t4.w) ? v.w : xt.w;
        }
        float4 s = make_float4(0.f, 0.f, 0.f, 0.f);
        #pragma unroll
        for (int c = 0; c < CCH; ++c) {
            s.x += __expf(x[c].x - m.x);
            s.y += __expf(x[c].y - m.y);
            s.z += __expf(x[c].z - m.z);
            s.w += __expf(x[c].w - m.w);
        }

        float4 l;
        l.x = (t4.x != 255) ? (__logf(s.x) + m.x - xt.x) : 0.f;
        l.y = (t4.y != 255) ? (__logf(s.y) + m.y - xt.y) : 0.f;
        l.z = (t4.z != 255) ? (__logf(s.z) + m.z - xt.z) : 0.f;
        l.w = (t4.w != 255) ? (__logf(s.w) + m.w - xt.w) : 0.f;
        l.x = fmaxf(l.x, 0.f); l.y = fmaxf(l.y, 0.f);     // keep bit-order valid
        l.z = fmaxf(l.z, 0.f); l.w = fmaxf(l.w, 0.f);
        loss4[i] = l;

        if (l.x > THRESH_F) { ls += l.x; lc++; }
        if (l.y > THRESH_F) { ls += l.y; lc++; }
        if (l.z > THRESH_F) { ls += l.z; lc++; }
        if (l.w > THRESH_F) { ls += l.w; lc++; }
        atomicAdd(&sh[__float_as_uint(l.x) >> 21], 1u);
        atomicAdd(&sh[__float_as_uint(l.y) >> 21], 1u);
        atomicAdd(&sh[__float_as_uint(l.z) >> 21], 1u);
        atomicAdd(&sh[__float_as_uint(l.w) >> 21], 1u);
    }

    // block-reduce ls / lc
    #pragma unroll
    for (int off = 32; off > 0; off >>= 1) {
        ls += __shfl_down(ls, off);
        lc += __shfl_down(lc, off);
    }
    __shared__ float wsum[4];
    __shared__ unsigned int wcnt[4];
    const int lane = threadIdx.x & 63, wid = threadIdx.x >> 6;
    if (lane == 0) { wsum[wid] = ls; wcnt[wid] = lc; }
    __syncthreads();
    if (threadIdx.x == 0) {
        atomicAdd(sumT, (double)(wsum[0] + wsum[1] + wsum[2] + wsum[3]));
        atomicAdd(cntT, (unsigned long long)(wcnt[0] + wcnt[1] + wcnt[2] + wcnt[3]));
    }

    __syncthreads();
    for (int i = threadIdx.x; i < NB1; i += 256) {
        unsigned int v = sh[i];
        if (v) atomicAdd(&hist1[i], v);   // skip-zero merge: hot bins only
    }
}

// ---------------- radix-select step (single block) -------------------------
// state.x = prefix bits so far, state.y = K remaining within current bucket
// Early-exit: if cntT > NMIN the threshold branch wins and select is dead work.
__global__ __launch_bounds__(256) void k_select(
    const unsigned int* __restrict__ hist, int nbins, int shiftbits, int first,
    uint2* __restrict__ state, const unsigned long long* __restrict__ cntT)
{
    if (*cntT > (unsigned long long)NMIN) return;   // cond==true path: unused

    __shared__ unsigned int cnt[NB1];
    __shared__ unsigned int psum[257];
    const int tid = threadIdx.x;

    for (int i = tid; i < nbins; i += 256) cnt[i] = hist[i];
    if (tid == 0) psum[256] = 0;
    __syncthreads();

    const int chunk = nbins >> 8;
    const int lo = tid * chunk, hi = lo + chunk;
    unsigned int s = 0;
    for (int b = lo; b < hi; ++b) s += cnt[b];
    psum[tid] = s;
    __syncthreads();

    // inclusive suffix-sum (Hillis-Steele)
    for (int d = 1; d < 256; d <<= 1) {
        unsigned int v = psum[tid] + ((tid + d < 256) ? psum[tid + d] : 0);
        __syncthreads();
        psum[tid] = v;
        __syncthreads();
    }

    const unsigned int K       = first ? (unsigned int)NMIN : state->y;
    const unsigned int oldpref = first ? 0u : state->x;
    __syncthreads();   // everyone has read old state before the winner writes

    const unsigned int above = psum[tid + 1];
    if (psum[tid] >= K && above < K) {          // crossing is in my chunk
        unsigned int cum = above;
        for (int b = hi - 1; b >= lo; --b) {
            const unsigned int prev = cum;
            cum += cnt[b];
            if (cum >= K) {
                state->x = (oldpref << shiftbits) | (unsigned int)b;
                state->y = K - prev;
                break;
            }
        }
    }
}

// ---------------- conditional histogram for levels 2/3 ---------------------
__global__ __launch_bounds__(256) void k_hist(
    const float4* __restrict__ loss4, const uint2* __restrict__ state,
    unsigned int* __restrict__ histo, int level,
    const unsigned long long* __restrict__ cntT)
{
    if (*cntT > (unsigned long long)NMIN) return;   // cond==true path: unused

    __shared__ unsigned int sh[NB2];
    const int nb = (level == 2) ? NB2 : NB3;
    for (int i = threadIdx.x; i < nb; i += 256) sh[i] = 0;
    __syncthreads();

    const unsigned int pref = state->x;
    const unsigned int stride = gridDim.x * 256;

    for (unsigned int i = blockIdx.x * 256 + threadIdx.x; i < NPIX / 4; i += stride) {
        const float4 v = loss4[i];
        const float vv[4] = {v.x, v.y, v.z, v.w};
        #pragma unroll
        for (int j = 0; j < 4; ++j) {
            const unsigned int bits = __float_as_uint(vv[j]);
            if (level == 2) {
                if ((bits >> 21) == pref) atomicAdd(&sh[(bits >> 10) & 0x7FF], 1u);
            } else {
                if ((bits >> 10) == pref) atomicAdd(&sh[bits & 0x3FF], 1u);
            }
        }
    }
    __syncthreads();
    for (int i = threadIdx.x; i < nb; i += 256) {
        unsigned int v = sh[i];
        if (v) atomicAdd(&histo[i], v);
    }
}

// ---------------- sum/count of elements strictly above t -------------------
__global__ __launch_bounds__(256) void k_sumtop(
    const float4* __restrict__ loss4, const uint2* __restrict__ state,
    double* __restrict__ sumG, unsigned long long* __restrict__ cntG,
    const unsigned long long* __restrict__ cntT)
{
    if (*cntT > (unsigned long long)NMIN) return;   // cond==true path: unused

    const unsigned int tb = state->x;   // full 32-bit pattern of t
    float ls = 0.f;
    unsigned int lc = 0;
    const unsigned int stride = gridDim.x * 256;

    for (unsigned int i = blockIdx.x * 256 + threadIdx.x; i < NPIX / 4; i += stride) {
        const float4 v = loss4[i];
        const float vv[4] = {v.x, v.y, v.z, v.w};
        #pragma unroll
        for (int j = 0; j < 4; ++j) {
            if (__float_as_uint(vv[j]) > tb) { ls += vv[j]; lc++; }
        }
    }
    #pragma unroll
    for (int off = 32; off > 0; off >>= 1) {
        ls += __shfl_down(ls, off);
        lc += __shfl_down(lc, off);
    }
    __shared__ float wsum[4];
    __shared__ unsigned int wcnt[4];
    const int lane = threadIdx.x & 63, wid = threadIdx.x >> 6;
    if (lane == 0) { wsum[wid] = ls; wcnt[wid] = lc; }
    __syncthreads();
    if (threadIdx.x == 0) {
        atomicAdd(sumG, (double)(wsum[0] + wsum[1] + wsum[2] + wsum[3]));
        atomicAdd(cntG, (unsigned long long)(wcnt[0] + wcnt[1] + wcnt[2] + wcnt[3]));
    }
}

// ---------------- finalize -------------------------------------------------
__global__ void k_finalize(
    const double* __restrict__ sumT, const unsigned long long* __restrict__ cntT,
    const uint2* __restrict__ state, const double* __restrict__ sumG,
    const unsigned long long* __restrict__ cntG, float* __restrict__ out)
{
    if (threadIdx.x == 0 && blockIdx.x == 0) {
        const unsigned long long c = *cntT;
        double r;
        if (c > (unsigned long long)NMIN) {
            r = *sumT / (double)c;                       // keep all > THRESH
        } else {
            const float t = __uint_as_float(state->x);   // N_MIN-th largest
            r = (*sumG + (double)(NMIN - *cntG) * (double)t) / (double)NMIN;
        }
        out[0] = (float)r;
    }
}

// ---------------- launch ---------------------------------------------------
extern "C" void kernel_launch(void* const* d_in, const int* in_sizes, int n_in,
                              void* d_out, int out_size, void* d_ws, size_t ws_size,
                              hipStream_t stream)
{
    const float* inp = (const float*)d_in[0];
    const int*   tgt = (const int*)d_in[1];
    float*       out = (float*)d_out;
    char*        ws  = (char*)d_ws;

    // workspace layout
    float* loss = (float*)ws;
    const size_t LOSS_BYTES = (size_t)NPIX * 4;                 // 16 MiB
    unsigned int* h1 = (unsigned int*)(ws + LOSS_BYTES);        // 2048
    unsigned int* h2 = h1 + NB1;                                // 2048
    unsigned int* h3 = h2 + NB2;                                // 1024
    char* scal = ws + LOSS_BYTES + (NB1 + NB2 + NB3) * 4;       // +20480
    double*             sumT  = (double*)(scal + 0);
    unsigned long long* cntT  = (unsigned long long*)(scal + 8);
    double*             sumG  = (double*)(scal + 16);
    unsigned long long* cntG  = (unsigned long long*)(scal + 24);
    uint2*              state = (uint2*)(scal + 32);
    const size_t AUX_BYTES = (NB1 + NB2 + NB3) * 4 + 40;

    // zero hists + accumulators (ws is poisoned 0xAA before every launch)
    hipMemsetAsync(ws + LOSS_BYTES, 0, AUX_BYTES, stream);

    // 1) CE loss + level-1 hist + above-threshold sum/count
    k_compute4<<<NBLK, 256, 0, stream>>>(inp, tgt, (float4*)loss, h1, sumT, cntT);
    // 2) radix select level 1 (top 11 bits) — skipped if cond==true
    k_select<<<1, 256, 0, stream>>>(h1, NB1, 11, 1, state, cntT);
    // 3) level-2 hist (next 11 bits) among candidates — skipped if cond==true
    k_hist<<<NBLK, 256, 0, stream>>>((const float4*)loss, state, h2, 2, cntT);
    k_select<<<1, 256, 0, stream>>>(h2, NB2, 11, 0, state, cntT);
    // 4) level-3 hist (last 10 bits) — skipped if cond==true
    k_hist<<<NBLK, 256, 0, stream>>>((const float4*)loss, state, h3, 3, cntT);
    k_select<<<1, 256, 0, stream>>>(h3, NB3, 10, 0, state, cntT);
    // 5) sum/count strictly above t — skipped if cond==true
    k_sumtop<<<NBLK, 256, 0, stream>>>((const float4*)loss, state, sumG, cntG, cntT);
    // 6) pick branch, write scalar
    k_finalize<<<1, 1, 0, stream>>>(sumT, cntT, state, sumG, cntG, out);
}